// Round 5
// baseline (394.468 us; speedup 1.0000x reference)
//
#include <hip/hip_runtime.h>
#include <hip/hip_bf16.h>
#include <math.h>

// Problem constants
#define B   64
#define S   256
#define DD  512
#define H   8
#define DH  64
#define BH  (B*H)   // 512

typedef short s16x8 __attribute__((ext_vector_type(8)));
typedef short s16x4 __attribute__((ext_vector_type(4)));
typedef float f32x4 __attribute__((ext_vector_type(4)));

typedef __attribute__((address_space(3))) unsigned int       lds_u32;
typedef __attribute__((address_space(1))) const unsigned int glb_u32;

__device__ __forceinline__ short f2bf(float f) {
    union { float f; unsigned u; } v; v.f = f;
    unsigned u = v.u;
    u += 0x7FFFu + ((u >> 16) & 1u);   // RNE
    return (short)(u >> 16);
}

__device__ __forceinline__ void glds16(const void* g, void* l) {
    __builtin_amdgcn_global_load_lds((glb_u32*)g, (lds_u32*)l, 16, 0, 0);
}

// ---------------------------------------------------------------------------
// P1: x (f32, 16384x512) -> xbf (bf16)
// ---------------------------------------------------------------------------
__global__ __launch_bounds__(256) void convert_x_kernel(
    const float* __restrict__ x, ushort* __restrict__ xbf)
{
    const int idx = blockIdx.x * 256 + threadIdx.x;
    const float4 f0 = *(const float4*)(x + (size_t)idx * 8);
    const float4 f1 = *(const float4*)(x + (size_t)idx * 8 + 4);
    s16x8 o = { f2bf(f0.x), f2bf(f0.y), f2bf(f0.z), f2bf(f0.w),
                f2bf(f1.x), f2bf(f1.y), f2bf(f1.z), f2bf(f1.w) };
    *(s16x8*)(xbf + (size_t)idx * 8) = o;
}

// ---------------------------------------------------------------------------
// P2: transpose+convert weights: wt[z][n][k] = w_z[k][n]  (bf16)
// ---------------------------------------------------------------------------
__global__ __launch_bounds__(256) void transpose_w_kernel(
    const float* __restrict__ wq, const float* __restrict__ wk,
    const float* __restrict__ wv, const float* __restrict__ wd,
    ushort* __restrict__ wt)
{
    __shared__ float tile[32][33];
    const int z = blockIdx.z;
    const float* w = (z == 0) ? wq : (z == 1) ? wk : (z == 2) ? wv : wd;
    const int k0 = blockIdx.y * 32, n0 = blockIdx.x * 32;
    const int tx = threadIdx.x & 31, ty = threadIdx.x >> 5;

    #pragma unroll
    for (int r = 0; r < 32; r += 8)
        tile[ty + r][tx] = w[(size_t)(k0 + ty + r) * DD + n0 + tx];
    __syncthreads();
    #pragma unroll
    for (int r = 0; r < 32; r += 8)
        wt[(size_t)z * DD * DD + (size_t)(n0 + ty + r) * DD + k0 + tx] =
            (ushort)f2bf(tile[tx][ty + r]);
}

// ---------------------------------------------------------------------------
// P2b: expanded Toeplitz B^T (combined conv kernels, /24 = conv/3 * score/8):
//   bt[c][r*256 + t] = kcomb[r][t - c + 127] / 24   (0 outside)
// 256x1280 bf16 = 640 KB, built once, L2-resident, shared by all blocks.
// ---------------------------------------------------------------------------
__global__ __launch_bounds__(256) void build_toeplitz_kernel(
    const float* __restrict__ c1k, const float* __restrict__ c3k,
    const float* __restrict__ c5k, ushort* __restrict__ bt)
{
    const int c = blockIdx.x;      // 0..255
    const int t = threadIdx.x;     // 0..255
    const int ki = t - c + 127;
    #pragma unroll
    for (int r = 0; r < 5; ++r) {
        float val = 0.f;
        if (ki >= 0 && ki < 256) {
            val = c5k[r * 256 + ki];
            if (r >= 1 && r <= 3) val += c3k[(r - 1) * 256 + ki];
            if (r == 2)           val += c1k[ki];
            val *= (1.f / 24.f);
        }
        bt[(size_t)c * 1280 + r * 256 + t] = (ushort)f2bf(val);
    }
}

// ---------------------------------------------------------------------------
// P3: bf16 MFMA GEMM, 128x128 tile, BK=64, 4 waves (2x2), m97 structure.
// MODE 0: qkv. z=0 -> q (B,H,S,DH); z=1 -> k (B,H,S,DH);
//              z=2 -> V TRANSPOSED: vbT[(bh*DH+dd)*S + ss]  (packed s16x4)
// MODE 1: dense -> f32 out = acc + bias[col].
// ---------------------------------------------------------------------------
template<int MODE>
__global__ __launch_bounds__(256) void gemm_mfma_kernel(
    const ushort* __restrict__ A, const ushort* __restrict__ BtAll,
    ushort* __restrict__ qo, ushort* __restrict__ ko, ushort* __restrict__ vo,
    const float* __restrict__ bias, float* __restrict__ outf)
{
    __shared__ ushort As[128 * 64];
    __shared__ ushort Bs[128 * 64];

    const int tid  = threadIdx.x;
    const int lane = tid & 63, w = tid >> 6;
    const int l15  = lane & 15, l4 = lane >> 4;
    const int wr   = w >> 1, wc = w & 1;
    const int row0 = blockIdx.y * 128, col0 = blockIdx.x * 128;
    const ushort* Bt = BtAll + (MODE == 0 ? (size_t)blockIdx.z * DD * DD : 0);

    f32x4 acc[4][4];
    #pragma unroll
    for (int mt = 0; mt < 4; ++mt)
        #pragma unroll
        for (int nt = 0; nt < 4; ++nt)
            acc[mt][nt] = (f32x4){0.f, 0.f, 0.f, 0.f};

    const int arow = tid >> 3;
    const int acol = (tid & 7) * 8;
    char* ldsA = (char*)As + (tid >> 6) * 1024;
    char* ldsB = (char*)Bs + (tid >> 6) * 1024;

    for (int k0 = 0; k0 < DD; k0 += 64) {
        #pragma unroll
        for (int i = 0; i < 4; ++i)
            glds16(A  + (size_t)(row0 + arow + 32 * i) * DD + k0 + acol,
                   ldsA + 4096 * i);
        #pragma unroll
        for (int i = 0; i < 4; ++i)
            glds16(Bt + (size_t)(col0 + arow + 32 * i) * DD + k0 + acol,
                   ldsB + 4096 * i);
        __syncthreads();

        #pragma unroll
        for (int kk = 0; kk < 2; ++kk) {
            s16x8 af[4], bf[4];
            #pragma unroll
            for (int mt = 0; mt < 4; ++mt) {
                const int row = wr * 64 + mt * 16 + l15;
                af[mt] = *(const s16x8*)((char*)As + row * 128 + kk * 64 + l4 * 16);
            }
            #pragma unroll
            for (int nt = 0; nt < 4; ++nt) {
                const int col = wc * 64 + nt * 16 + l15;
                bf[nt] = *(const s16x8*)((char*)Bs + col * 128 + kk * 64 + l4 * 16);
            }
            #pragma unroll
            for (int mt = 0; mt < 4; ++mt)
                #pragma unroll
                for (int nt = 0; nt < 4; ++nt)
                    acc[mt][nt] = __builtin_amdgcn_mfma_f32_16x16x32_bf16(
                                      af[mt], bf[nt], acc[mt][nt], 0, 0, 0);
        }
        __syncthreads();
    }

    if (MODE == 0) {
        if (blockIdx.z == 2) {
            // V transposed, packed 4 consecutive ss per write
            #pragma unroll
            for (int mt = 0; mt < 4; ++mt)
                #pragma unroll
                for (int nt = 0; nt < 4; ++nt) {
                    const int r = row0 + wr * 64 + mt * 16 + l4 * 4;
                    const int c = col0 + wc * 64 + nt * 16 + l15;
                    const int bb = r >> 8, ss = r & 255;
                    const int hh = c >> 6, dd = c & 63;
                    s16x4 pk = { f2bf(acc[mt][nt][0]), f2bf(acc[mt][nt][1]),
                                 f2bf(acc[mt][nt][2]), f2bf(acc[mt][nt][3]) };
                    *(s16x4*)(vo + ((size_t)((bb * H + hh) * DH + dd)) * S + ss) = pk;
                }
        } else {
            ushort* dst = (blockIdx.z == 0) ? qo : ko;
            #pragma unroll
            for (int mt = 0; mt < 4; ++mt)
                #pragma unroll
                for (int nt = 0; nt < 4; ++nt)
                    #pragma unroll
                    for (int rg = 0; rg < 4; ++rg) {
                        const int r = row0 + wr * 64 + mt * 16 + l4 * 4 + rg;
                        const int c = col0 + wc * 64 + nt * 16 + l15;
                        const int bb = r >> 8, ss = r & 255;
                        const int hh = c >> 6, dd = c & 63;
                        dst[(((size_t)(bb * H + hh)) * S + ss) * DH + dd] =
                            (ushort)f2bf(acc[mt][nt][rg]);
                    }
        }
    } else {
        #pragma unroll
        for (int mt = 0; mt < 4; ++mt)
            #pragma unroll
            for (int nt = 0; nt < 4; ++nt)
                #pragma unroll
                for (int rg = 0; rg < 4; ++rg) {
                    const int r = row0 + wr * 64 + mt * 16 + l4 * 4 + rg;
                    const int c = col0 + wc * 64 + nt * 16 + l15;
                    outf[(size_t)r * DD + c] = acc[mt][nt][rg] + bias[c];
                }
    }
}

// ---------------------------------------------------------------------------
// K2: pairwise features + tiny MLP -> m[b][i][j]  (unchanged, known-good)
// ---------------------------------------------------------------------------
__global__ __launch_bounds__(256) void pairwise_mlp_kernel(
    const float* __restrict__ particles,
    const float* __restrict__ mw1, const float* __restrict__ mb1,
    const float* __restrict__ mw2, const float* __restrict__ mb2,
    const float* __restrict__ mw3, const float* __restrict__ mb3,
    float* __restrict__ mbuf)
{
    __shared__ float w1[32], b1[8], w2[64], b2[8], w3[8];
    __shared__ float b3s;
    const int tid = threadIdx.x;
    if (tid < 32)                 w1[tid]        = mw1[tid];
    if (tid >= 32 && tid < 40)    b1[tid - 32]   = mb1[tid - 32];
    if (tid >= 64 && tid < 128)   w2[tid - 64]   = mw2[tid - 64];
    if (tid >= 128 && tid < 136)  b2[tid - 128]  = mb2[tid - 128];
    if (tid >= 136 && tid < 144)  w3[tid - 136]  = mw3[tid - 136];
    if (tid == 144)               b3s            = mb3[0];

    const int bi = blockIdx.x;
    const int bb = bi >> 8;
    const float pt_i  = particles[(size_t)bi * 3 + 0];
    const float eta_i = particles[(size_t)bi * 3 + 1];
    const float phi_i = particles[(size_t)bi * 3 + 2];

    const int j = tid;
    const float* pj = particles + ((size_t)(bb * S) + j) * 3;
    const float pt_j = pj[0], eta_j = pj[1], phi_j = pj[2];

    __syncthreads();

    const float d_eta = eta_i - eta_j;
    const float dp    = phi_i - phi_j;
    const float d_phi = atan2f(sinf(dp), cosf(dp));
    const float delta = sqrtf(d_eta * d_eta + d_phi * d_phi);
    const float min_pt = fminf(pt_i, pt_j);
    const float kT = min_pt * delta;
    const float zf = min_pt / (pt_i + pt_j + 1e-8f);
    const float cd = cosf(d_phi);
    const float m2 = fmaxf(pt_i * pt_i + pt_j * pt_j - 2.0f * pt_i * pt_j * cd, 1e-8f);

    const float eps = 1e-8f;
    const float f[4] = { logf(fmaxf(delta, eps)),
                         logf(fmaxf(kT,    eps)),
                         logf(fmaxf(zf,    eps)),
                         logf(m2) };

    float h1[8];
    #pragma unroll
    for (int o = 0; o < 8; ++o) {
        float s = b1[o];
        #pragma unroll
        for (int i4 = 0; i4 < 4; ++i4) s += f[i4] * w1[i4 * 8 + o];
        h1[o] = fmaxf(s, 0.0f);
    }
    float h2[8];
    #pragma unroll
    for (int o = 0; o < 8; ++o) {
        float s = b2[o];
        #pragma unroll
        for (int i8 = 0; i8 < 8; ++i8) s += h1[i8] * w2[i8 * 8 + o];
        h2[o] = fmaxf(s, 0.0f);
    }
    float mv = b3s;
    #pragma unroll
    for (int i8 = 0; i8 < 8; ++i8) mv += h2[i8] * w3[i8];
    mv = fminf(fmaxf(mv, -10.0f), 10.0f);

    mbuf[(size_t)bi * S + j] = mv;
}

// ---------------------------------------------------------------------------
// K3: MFMA-fused  scores -> Toeplitz conv -> +bias+m -> softmax -> PV
// Conv B-frags from global Toeplitz bt (L2-resident); PV B-frags from global
// vbT (L1-resident per head).  LDS = 40 KB: SC [80][512B] swizzled; RED in
// SC halo rows 74-75 (conv reads only rows 6..73); PB aliases SC rows 0-63.
// ---------------------------------------------------------------------------
__global__ __launch_bounds__(256, 3) void fused_mfma_kernel(
    const ushort* __restrict__ q, const ushort* __restrict__ kbuf,
    const ushort* __restrict__ vbT, const ushort* __restrict__ bt,
    const float* __restrict__ c1b, const float* __restrict__ c3b,
    const float* __restrict__ c5b,
    const float* __restrict__ mbuf, ushort* __restrict__ attn)
{
    __shared__ __align__(16) char pool[40960];
    char* SC  = pool;                       // scores bf16 [80][512B], swizzled
    char* PB  = pool;                       // P bf16 [64][512B] (aliases SC)
    float* RED = (float*)(pool + 37888);    // [64][4] (SC rows 74-75, unused by conv)

    const int tid  = threadIdx.x;
    const int lane = tid & 63;
    const int w    = tid >> 6;
    const int l15  = lane & 15, l4 = lane >> 4;
    const int head = blockIdx.y;            // b*H + h
    const int bb   = head >> 3, hh = head & 7;
    const int i0   = blockIdx.x * 64;
    const int cb   = w * 64;                // this wave's column base

    // ---- phase 1: scores rows i0-8 .. i0+71 (80 rows), unscaled ----
    {
        const ushort* kb_h = kbuf + (size_t)head * S * DH;
        const ushort* qb_h = q    + (size_t)head * S * DH;
        #pragma unroll
        for (int rt = 0; rt < 5; ++rt) {
            const int qrow = i0 - 8 + rt * 16 + l15;
            const bool qok = ((unsigned)qrow < (unsigned)S);
            f32x4 sacc[4];
            #pragma unroll
            for (int n = 0; n < 4; ++n) sacc[n] = (f32x4){0.f, 0.f, 0.f, 0.f};
            #pragma unroll
            for (int kk = 0; kk < 2; ++kk) {
                s16x8 afr = (s16x8){0,0,0,0,0,0,0,0};
                if (qok)
                    afr = *(const s16x8*)(qb_h + (size_t)qrow * 64 + kk * 32 + 8 * l4);
                #pragma unroll
                for (int n = 0; n < 4; ++n) {
                    const s16x8 bfr = *(const s16x8*)(kb_h
                                      + (size_t)(cb + n * 16 + l15) * 64 + kk * 32 + 8 * l4);
                    sacc[n] = __builtin_amdgcn_mfma_f32_16x16x32_bf16(
                                  afr, bfr, sacc[n], 0, 0, 0);
                }
            }
            #pragma unroll
            for (int n = 0; n < 4; ++n)
                #pragma unroll
                for (int rg = 0; rg < 4; ++rg) {
                    const int srow = rt * 16 + l4 * 4 + rg;
                    const int col  = cb + n * 16 + l15;
                    const int byt  = (srow * 512 + col * 2) ^ ((srow & 7) << 4);
                    *(short*)(SC + byt) = f2bf(sacc[n][rg]);
                }
        }
    }
    __syncthreads();

    // ---- phase 2: Toeplitz conv; B-frags from global bt, 1-ahead prefetch ----
    f32x4 cacc[4][4];
    #pragma unroll
    for (int rt = 0; rt < 4; ++rt)
        #pragma unroll
        for (int n = 0; n < 4; ++n)
            cacc[rt][n] = (f32x4){0.f, 0.f, 0.f, 0.f};

    {
        const ushort* btl = bt + (size_t)(cb + l15) * 1280 + 8 * l4;

        auto ldB = [&](int st, s16x8* d) {
            const ushort* p = btl + (st >> 3) * 256 + (st & 7) * 32;
            d[0] = *(const s16x8*)(p);
            d[1] = *(const s16x8*)(p + 20480);   // +16 cols * 1280
            d[2] = *(const s16x8*)(p + 40960);
            d[3] = *(const s16x8*)(p + 61440);
        };
        auto convStep = [&](int st, const s16x8* bfr) {
            const int r = st >> 3, kb2 = (st & 7) * 64 + 16 * l4;
            #pragma unroll
            for (int rt = 0; rt < 4; ++rt) {
                const int sr  = rt * 16 + l15 + r + 6;
                const s16x8 afr = *(const s16x8*)(SC + ((sr * 512 + kb2) ^ ((sr & 7) << 4)));
                cacc[rt][0] = __builtin_amdgcn_mfma_f32_16x16x32_bf16(afr, bfr[0], cacc[rt][0], 0, 0, 0);
                cacc[rt][1] = __builtin_amdgcn_mfma_f32_16x16x32_bf16(afr, bfr[1], cacc[rt][1], 0, 0, 0);
                cacc[rt][2] = __builtin_amdgcn_mfma_f32_16x16x32_bf16(afr, bfr[2], cacc[rt][2], 0, 0, 0);
                cacc[rt][3] = __builtin_amdgcn_mfma_f32_16x16x32_bf16(afr, bfr[3], cacc[rt][3], 0, 0, 0);
            }
        };

        s16x8 bA[4], bB[4];
        ldB(0, bA);
        for (int s2 = 0; s2 < 20; ++s2) {
            ldB(2 * s2 + 1, bB);
            convStep(2 * s2, bA);
            if (s2 < 19) ldB(2 * s2 + 2, bA);
            convStep(2 * s2 + 1, bB);
        }
    }

    // ---- phase 2.5: + combined bias + m ----
    {
        const float bias_comb = (c1b[0] + c3b[0] + c5b[0]) * (1.f / 3.f);
        const float* mrow = mbuf + (size_t)bb * 65536;
        #pragma unroll
        for (int rt = 0; rt < 4; ++rt)
            #pragma unroll
            for (int rg = 0; rg < 4; ++rg) {
                const int i = i0 + rt * 16 + l4 * 4 + rg;
                #pragma unroll
                for (int n = 0; n < 4; ++n) {
                    const int j = cb + n * 16 + l15;
                    cacc[rt][n][rg] += bias_comb + mrow[i * 256 + j];
                }
            }
    }

    // ---- phase 3: softmax ----
    float rmax[4][4];
    #pragma unroll
    for (int rt = 0; rt < 4; ++rt)
        #pragma unroll
        for (int rg = 0; rg < 4; ++rg) {
            float mx = fmaxf(fmaxf(cacc[rt][0][rg], cacc[rt][1][rg]),
                             fmaxf(cacc[rt][2][rg], cacc[rt][3][rg]));
            mx = fmaxf(mx, __shfl_xor(mx, 1));
            mx = fmaxf(mx, __shfl_xor(mx, 2));
            mx = fmaxf(mx, __shfl_xor(mx, 4));
            mx = fmaxf(mx, __shfl_xor(mx, 8));
            rmax[rt][rg] = mx;
        }
    if (l15 == 0) {
        #pragma unroll
        for (int rt = 0; rt < 4; ++rt)
            #pragma unroll
            for (int rg = 0; rg < 4; ++rg)
                RED[(rt * 16 + l4 * 4 + rg) * 4 + w] = rmax[rt][rg];
    }
    __syncthreads();
    #pragma unroll
    for (int rt = 0; rt < 4; ++rt)
        #pragma unroll
        for (int rg = 0; rg < 4; ++rg) {
            const int row = rt * 16 + l4 * 4 + rg;
            rmax[rt][rg] = fmaxf(fmaxf(RED[row * 4 + 0], RED[row * 4 + 1]),
                                 fmaxf(RED[row * 4 + 2], RED[row * 4 + 3]));
        }
    __syncthreads();

    float rinv[4][4];
    #pragma unroll
    for (int rt = 0; rt < 4; ++rt)
        #pragma unroll
        for (int rg = 0; rg < 4; ++rg) {
            float sm = 0.f;
            #pragma unroll
            for (int n = 0; n < 4; ++n) {
                const float e = __expf(cacc[rt][n][rg] - rmax[rt][rg]);
                cacc[rt][n][rg] = e;
                sm += e;
            }
            sm += __shfl_xor(sm, 1);
            sm += __shfl_xor(sm, 2);
            sm += __shfl_xor(sm, 4);
            sm += __shfl_xor(sm, 8);
            rinv[rt][rg] = sm;
        }
    if (l15 == 0) {
        #pragma unroll
        for (int rt = 0; rt < 4; ++rt)
            #pragma unroll
            for (int rg = 0; rg < 4; ++rg)
                RED[(rt * 16 + l4 * 4 + rg) * 4 + w] = rinv[rt][rg];
    }
    __syncthreads();
    #pragma unroll
    for (int rt = 0; rt < 4; ++rt)
        #pragma unroll
        for (int rg = 0; rg < 4; ++rg) {
            const int row = rt * 16 + l4 * 4 + rg;
            const float tot = (RED[row * 4 + 0] + RED[row * 4 + 1])
                            + (RED[row * 4 + 2] + RED[row * 4 + 3]);
            rinv[rt][rg] = 1.f / tot;
        }
    __syncthreads();   // all conv SC-reads & RED reads done before PB overwrite

    // ---- write P (bf16, swizzled, aliases SC rows 0-63) ----
    #pragma unroll
    for (int rt = 0; rt < 4; ++rt)
        #pragma unroll
        for (int n = 0; n < 4; ++n)
            #pragma unroll
            for (int rg = 0; rg < 4; ++rg) {
                const int row = rt * 16 + l4 * 4 + rg;
                const int col = cb + n * 16 + l15;
                const int byt = (row * 512 + col * 2) ^ ((row & 7) << 4);
                *(short*)(PB + byt) = f2bf(cacc[rt][n][rg] * rinv[rt][rg]);
            }
    __syncthreads();

    // ---- phase 4: PV via MFMA; B-frags from global vbT ----
    const ushort* vt_h = vbT + (size_t)head * DH * S;
    f32x4 pacc[4];
    #pragma unroll
    for (int n = 0; n < 4; ++n) pacc[n] = (f32x4){0.f, 0.f, 0.f, 0.f};
    #pragma unroll
    for (int kk = 0; kk < 8; ++kk) {
        const int prow = w * 16 + l15;
        const int byta = (prow * 512 + kk * 64 + 16 * l4) ^ ((prow & 7) << 4);
        const s16x8 pa = *(const s16x8*)(PB + byta);
        #pragma unroll
        for (int n = 0; n < 4; ++n) {
            const s16x8 vb8 = *(const s16x8*)(vt_h
                              + (size_t)(n * 16 + l15) * S + kk * 32 + 8 * l4);
            pacc[n] = __builtin_amdgcn_mfma_f32_16x16x32_bf16(pa, vb8, pacc[n], 0, 0, 0);
        }
    }
    #pragma unroll
    for (int n = 0; n < 4; ++n)
        #pragma unroll
        for (int rg = 0; rg < 4; ++rg) {
            const int i = i0 + w * 16 + l4 * 4 + rg;
            const int d = n * 16 + l15;
            attn[(((size_t)bb * S + i) * H + hh) * DH + d] = (ushort)f2bf(pacc[n][rg]);
        }
}

// ---------------------------------------------------------------------------
// launcher
// ---------------------------------------------------------------------------
extern "C" void kernel_launch(void* const* d_in, const int* in_sizes, int n_in,
                              void* d_out, int out_size, void* d_ws, size_t ws_size,
                              hipStream_t stream)
{
    (void)in_sizes; (void)n_in; (void)out_size; (void)ws_size;

    const float* x        = (const float*)d_in[0];
    const float* particles= (const float*)d_in[1];
    const float* wq       = (const float*)d_in[2];
    const float* wk       = (const float*)d_in[3];
    const float* wv       = (const float*)d_in[4];
    const float* dense_w  = (const float*)d_in[5];
    const float* dense_b  = (const float*)d_in[6];
    const float* c1k      = (const float*)d_in[7];
    const float* c1b      = (const float*)d_in[8];
    const float* c3k      = (const float*)d_in[9];
    const float* c3b      = (const float*)d_in[10];
    const float* c5k      = (const float*)d_in[11];
    const float* c5b      = (const float*)d_in[12];
    const float* mw1      = (const float*)d_in[13];
    const float* mb1      = (const float*)d_in[14];
    const float* mw2      = (const float*)d_in[15];
    const float* mb2      = (const float*)d_in[16];
    const float* mw3      = (const float*)d_in[17];
    const float* mb3      = (const float*)d_in[18];
    float* out = (float*)d_out;

    // workspace layout (ushort units unless noted), total ~103 MB
    ushort* xbf   = (ushort*)d_ws;                       //  8,388,608
    ushort* wt    = xbf   + (size_t)8388608;             //  1,048,576
    ushort* qb    = wt    + (size_t)1048576;             //  8,388,608
    ushort* kb    = qb    + (size_t)8388608;             //  8,388,608
    ushort* vbT   = kb    + (size_t)8388608;             //  8,388,608  [BH][DH][S]
    ushort* attnb = vbT   + (size_t)8388608;             //  8,388,608
    ushort* bt    = attnb + (size_t)8388608;             //    327,680  [256][1280]
    float*  mb    = (float*)(bt + (size_t)327680);       //  4,194,304 f32

    convert_x_kernel<<<dim3(4096), 256, 0, stream>>>(x, xbf);
    transpose_w_kernel<<<dim3(16, 16, 4), 256, 0, stream>>>(wq, wk, wv, dense_w, wt);
    build_toeplitz_kernel<<<dim3(256), 256, 0, stream>>>(c1k, c3k, c5k, bt);
    pairwise_mlp_kernel<<<dim3(B * S), 256, 0, stream>>>(particles, mw1, mb1, mw2, mb2, mw3, mb3, mb);

    gemm_mfma_kernel<0><<<dim3(4, 128, 3), 256, 0, stream>>>(
        xbf, wt, qb, kb, vbT, nullptr, nullptr);

    fused_mfma_kernel<<<dim3(4, BH), 256, 0, stream>>>(
        qb, kb, vbT, bt, c1b, c3b, c5b, mb, attnb);

    gemm_mfma_kernel<1><<<dim3(4, 128, 1), 256, 0, stream>>>(
        attnb, wt + (size_t)3 * DD * DD, nullptr, nullptr, nullptr, dense_b, out);
}

// Round 6
// 330.994 us; speedup vs baseline: 1.1918x; 1.1918x over previous
//
#include <hip/hip_runtime.h>
#include <hip/hip_bf16.h>
#include <math.h>

// Problem constants
#define B   64
#define S   256
#define DD  512
#define H   8
#define DH  64
#define BH  (B*H)   // 512

typedef short s16x8 __attribute__((ext_vector_type(8)));
typedef short s16x4 __attribute__((ext_vector_type(4)));
typedef float f32x4 __attribute__((ext_vector_type(4)));

typedef __attribute__((address_space(3))) unsigned int       lds_u32;
typedef __attribute__((address_space(1))) const unsigned int glb_u32;

__device__ __forceinline__ short f2bf(float f) {
    union { float f; unsigned u; } v; v.f = f;
    unsigned u = v.u;
    u += 0x7FFFu + ((u >> 16) & 1u);   // RNE
    return (short)(u >> 16);
}

__device__ __forceinline__ void glds16(const void* g, void* l) {
    __builtin_amdgcn_global_load_lds((glb_u32*)g, (lds_u32*)l, 16, 0, 0);
}

// ---------------------------------------------------------------------------
// P1: x (f32, 16384x512) -> xbf (bf16)
// ---------------------------------------------------------------------------
__global__ __launch_bounds__(256) void convert_x_kernel(
    const float* __restrict__ x, ushort* __restrict__ xbf)
{
    const int idx = blockIdx.x * 256 + threadIdx.x;
    const float4 f0 = *(const float4*)(x + (size_t)idx * 8);
    const float4 f1 = *(const float4*)(x + (size_t)idx * 8 + 4);
    s16x8 o = { f2bf(f0.x), f2bf(f0.y), f2bf(f0.z), f2bf(f0.w),
                f2bf(f1.x), f2bf(f1.y), f2bf(f1.z), f2bf(f1.w) };
    *(s16x8*)(xbf + (size_t)idx * 8) = o;
}

// ---------------------------------------------------------------------------
// P2: transpose+convert weights: wt[z][n][k] = w_z[k][n]  (bf16)
// ---------------------------------------------------------------------------
__global__ __launch_bounds__(256) void transpose_w_kernel(
    const float* __restrict__ wq, const float* __restrict__ wk,
    const float* __restrict__ wv, const float* __restrict__ wd,
    ushort* __restrict__ wt)
{
    __shared__ float tile[32][33];
    const int z = blockIdx.z;
    const float* w = (z == 0) ? wq : (z == 1) ? wk : (z == 2) ? wv : wd;
    const int k0 = blockIdx.y * 32, n0 = blockIdx.x * 32;
    const int tx = threadIdx.x & 31, ty = threadIdx.x >> 5;

    #pragma unroll
    for (int r = 0; r < 32; r += 8)
        tile[ty + r][tx] = w[(size_t)(k0 + ty + r) * DD + n0 + tx];
    __syncthreads();
    #pragma unroll
    for (int r = 0; r < 32; r += 8)
        wt[(size_t)z * DD * DD + (size_t)(n0 + ty + r) * DD + k0 + tx] =
            (ushort)f2bf(tile[tx][ty + r]);
}

// ---------------------------------------------------------------------------
// P2b: Toeplitz B in MFMA-FRAGMENT-LINEAR order (so the consuming wave load
// is base + lane*16, fully coalesced):
//   btf[((n*40 + st)*64 + lane)*8 + e] = kcomb[r][t - c + 127] / 24
//   where c = n*16 + (lane&15), r = st>>3, t = (st&7)*32 + (lane>>4)*8 + e.
// 640 KB total, built once, L2-resident, shared by all 2048 fused blocks.
// ---------------------------------------------------------------------------
__global__ __launch_bounds__(256) void build_toeplitz_frag_kernel(
    const float* __restrict__ c1k, const float* __restrict__ c3k,
    const float* __restrict__ c5k, ushort* __restrict__ btf)
{
    const int idx  = blockIdx.x * 256 + threadIdx.x;   // 0..40959
    const int lane = idx & 63;
    const int st   = (idx >> 6) % 40;
    const int n    = idx / (40 * 64);
    const int c    = n * 16 + (lane & 15);
    const int r    = st >> 3;
    const int tb   = (st & 7) * 32 + (lane >> 4) * 8;

    s16x8 o;
    #pragma unroll
    for (int e = 0; e < 8; ++e) {
        const int ki = tb + e - c + 127;
        float val = 0.f;
        if (ki >= 0 && ki < 256) {
            val = c5k[r * 256 + ki];
            if (r >= 1 && r <= 3) val += c3k[(r - 1) * 256 + ki];
            if (r == 2)           val += c1k[ki];
            val *= (1.f / 24.f);
        }
        o[e] = f2bf(val);
    }
    *(s16x8*)(btf + (size_t)idx * 8) = o;
}

// ---------------------------------------------------------------------------
// P2c: repack vbT -> PV-fragment-linear vfrag:
//   vfrag[(((head*4 + n)*8 + kk)*64 + lane)*8 + e] =
//       vbT[(head*64 + n*16 + (lane&15))*256 + kk*32 + (lane>>4)*8 + e]
// ---------------------------------------------------------------------------
__global__ __launch_bounds__(256) void vfrag_repack_kernel(
    const ushort* __restrict__ vbT, ushort* __restrict__ vfrag)
{
    const int idx  = blockIdx.x * 256 + threadIdx.x;   // 0..1048575
    const int lane = idx & 63;
    const int kk   = (idx >> 6) & 7;
    const int n    = (idx >> 9) & 3;
    const int head = idx >> 11;
    const s16x8 v = *(const s16x8*)(vbT
        + ((size_t)(head * 64 + n * 16 + (lane & 15))) * 256
        + kk * 32 + (lane >> 4) * 8);
    *(s16x8*)(vfrag + (size_t)idx * 8) = v;
}

// ---------------------------------------------------------------------------
// P3: bf16 MFMA GEMM, 128x128 tile, BK=64, 4 waves (2x2), m97 structure.
// MODE 0: qkv. z=0 -> q (B,H,S,DH); z=1 -> k (B,H,S,DH);
//              z=2 -> V TRANSPOSED: vbT[(bh*DH+dd)*S + ss]  (packed s16x4)
// MODE 1: dense -> f32 out = acc + bias[col].
// ---------------------------------------------------------------------------
template<int MODE>
__global__ __launch_bounds__(256) void gemm_mfma_kernel(
    const ushort* __restrict__ A, const ushort* __restrict__ BtAll,
    ushort* __restrict__ qo, ushort* __restrict__ ko, ushort* __restrict__ vo,
    const float* __restrict__ bias, float* __restrict__ outf)
{
    __shared__ ushort As[128 * 64];
    __shared__ ushort Bs[128 * 64];

    const int tid  = threadIdx.x;
    const int lane = tid & 63, w = tid >> 6;
    const int l15  = lane & 15, l4 = lane >> 4;
    const int wr   = w >> 1, wc = w & 1;
    const int row0 = blockIdx.y * 128, col0 = blockIdx.x * 128;
    const ushort* Bt = BtAll + (MODE == 0 ? (size_t)blockIdx.z * DD * DD : 0);

    f32x4 acc[4][4];
    #pragma unroll
    for (int mt = 0; mt < 4; ++mt)
        #pragma unroll
        for (int nt = 0; nt < 4; ++nt)
            acc[mt][nt] = (f32x4){0.f, 0.f, 0.f, 0.f};

    const int arow = tid >> 3;
    const int acol = (tid & 7) * 8;
    char* ldsA = (char*)As + (tid >> 6) * 1024;
    char* ldsB = (char*)Bs + (tid >> 6) * 1024;

    for (int k0 = 0; k0 < DD; k0 += 64) {
        #pragma unroll
        for (int i = 0; i < 4; ++i)
            glds16(A  + (size_t)(row0 + arow + 32 * i) * DD + k0 + acol,
                   ldsA + 4096 * i);
        #pragma unroll
        for (int i = 0; i < 4; ++i)
            glds16(Bt + (size_t)(col0 + arow + 32 * i) * DD + k0 + acol,
                   ldsB + 4096 * i);
        __syncthreads();

        #pragma unroll
        for (int kk = 0; kk < 2; ++kk) {
            s16x8 af[4], bf[4];
            #pragma unroll
            for (int mt = 0; mt < 4; ++mt) {
                const int row = wr * 64 + mt * 16 + l15;
                af[mt] = *(const s16x8*)((char*)As + row * 128 + kk * 64 + l4 * 16);
            }
            #pragma unroll
            for (int nt = 0; nt < 4; ++nt) {
                const int col = wc * 64 + nt * 16 + l15;
                bf[nt] = *(const s16x8*)((char*)Bs + col * 128 + kk * 64 + l4 * 16);
            }
            #pragma unroll
            for (int mt = 0; mt < 4; ++mt)
                #pragma unroll
                for (int nt = 0; nt < 4; ++nt)
                    acc[mt][nt] = __builtin_amdgcn_mfma_f32_16x16x32_bf16(
                                      af[mt], bf[nt], acc[mt][nt], 0, 0, 0);
        }
        __syncthreads();
    }

    if (MODE == 0) {
        if (blockIdx.z == 2) {
            #pragma unroll
            for (int mt = 0; mt < 4; ++mt)
                #pragma unroll
                for (int nt = 0; nt < 4; ++nt) {
                    const int r = row0 + wr * 64 + mt * 16 + l4 * 4;
                    const int c = col0 + wc * 64 + nt * 16 + l15;
                    const int bb = r >> 8, ss = r & 255;
                    const int hh = c >> 6, dd = c & 63;
                    s16x4 pk = { f2bf(acc[mt][nt][0]), f2bf(acc[mt][nt][1]),
                                 f2bf(acc[mt][nt][2]), f2bf(acc[mt][nt][3]) };
                    *(s16x4*)(vo + ((size_t)((bb * H + hh) * DH + dd)) * S + ss) = pk;
                }
        } else {
            ushort* dst = (blockIdx.z == 0) ? qo : ko;
            #pragma unroll
            for (int mt = 0; mt < 4; ++mt)
                #pragma unroll
                for (int nt = 0; nt < 4; ++nt)
                    #pragma unroll
                    for (int rg = 0; rg < 4; ++rg) {
                        const int r = row0 + wr * 64 + mt * 16 + l4 * 4 + rg;
                        const int c = col0 + wc * 64 + nt * 16 + l15;
                        const int bb = r >> 8, ss = r & 255;
                        const int hh = c >> 6, dd = c & 63;
                        dst[(((size_t)(bb * H + hh)) * S + ss) * DH + dd] =
                            (ushort)f2bf(acc[mt][nt][rg]);
                    }
        }
    } else {
        #pragma unroll
        for (int mt = 0; mt < 4; ++mt)
            #pragma unroll
            for (int nt = 0; nt < 4; ++nt)
                #pragma unroll
                for (int rg = 0; rg < 4; ++rg) {
                    const int r = row0 + wr * 64 + mt * 16 + l4 * 4 + rg;
                    const int c = col0 + wc * 64 + nt * 16 + l15;
                    outf[(size_t)r * DD + c] = acc[mt][nt][rg] + bias[c];
                }
    }
}

// ---------------------------------------------------------------------------
// K2: pairwise features + tiny MLP -> m[b][i][j]  (unchanged, known-good)
// ---------------------------------------------------------------------------
__global__ __launch_bounds__(256) void pairwise_mlp_kernel(
    const float* __restrict__ particles,
    const float* __restrict__ mw1, const float* __restrict__ mb1,
    const float* __restrict__ mw2, const float* __restrict__ mb2,
    const float* __restrict__ mw3, const float* __restrict__ mb3,
    float* __restrict__ mbuf)
{
    __shared__ float w1[32], b1[8], w2[64], b2[8], w3[8];
    __shared__ float b3s;
    const int tid = threadIdx.x;
    if (tid < 32)                 w1[tid]        = mw1[tid];
    if (tid >= 32 && tid < 40)    b1[tid - 32]   = mb1[tid - 32];
    if (tid >= 64 && tid < 128)   w2[tid - 64]   = mw2[tid - 64];
    if (tid >= 128 && tid < 136)  b2[tid - 128]  = mb2[tid - 128];
    if (tid >= 136 && tid < 144)  w3[tid - 136]  = mw3[tid - 136];
    if (tid == 144)               b3s            = mb3[0];

    const int bi = blockIdx.x;
    const int bb = bi >> 8;
    const float pt_i  = particles[(size_t)bi * 3 + 0];
    const float eta_i = particles[(size_t)bi * 3 + 1];
    const float phi_i = particles[(size_t)bi * 3 + 2];

    const int j = tid;
    const float* pj = particles + ((size_t)(bb * S) + j) * 3;
    const float pt_j = pj[0], eta_j = pj[1], phi_j = pj[2];

    __syncthreads();

    const float d_eta = eta_i - eta_j;
    const float dp    = phi_i - phi_j;
    const float d_phi = atan2f(sinf(dp), cosf(dp));
    const float delta = sqrtf(d_eta * d_eta + d_phi * d_phi);
    const float min_pt = fminf(pt_i, pt_j);
    const float kT = min_pt * delta;
    const float zf = min_pt / (pt_i + pt_j + 1e-8f);
    const float cd = cosf(d_phi);
    const float m2 = fmaxf(pt_i * pt_i + pt_j * pt_j - 2.0f * pt_i * pt_j * cd, 1e-8f);

    const float eps = 1e-8f;
    const float f[4] = { logf(fmaxf(delta, eps)),
                         logf(fmaxf(kT,    eps)),
                         logf(fmaxf(zf,    eps)),
                         logf(m2) };

    float h1[8];
    #pragma unroll
    for (int o = 0; o < 8; ++o) {
        float s = b1[o];
        #pragma unroll
        for (int i4 = 0; i4 < 4; ++i4) s += f[i4] * w1[i4 * 8 + o];
        h1[o] = fmaxf(s, 0.0f);
    }
    float h2[8];
    #pragma unroll
    for (int o = 0; o < 8; ++o) {
        float s = b2[o];
        #pragma unroll
        for (int i8 = 0; i8 < 8; ++i8) s += h1[i8] * w2[i8 * 8 + o];
        h2[o] = fmaxf(s, 0.0f);
    }
    float mv = b3s;
    #pragma unroll
    for (int i8 = 0; i8 < 8; ++i8) mv += h2[i8] * w3[i8];
    mv = fminf(fmaxf(mv, -10.0f), 10.0f);

    mbuf[(size_t)bi * S + j] = mv;
}

// ---------------------------------------------------------------------------
// K3: MFMA-fused  scores -> Toeplitz conv -> +bias+m -> softmax -> PV
// Conv B from btf (fragment-linear, coalesced, depth-2 prefetch);
// PV B from vfrag (fragment-linear, coalesced).
// LDS = 40 KB: SC [80][512B] swizzled; RED in SC rows 74-75; PB aliases SC.
// ---------------------------------------------------------------------------
__global__ __launch_bounds__(256, 3) void fused_mfma_kernel(
    const ushort* __restrict__ q, const ushort* __restrict__ kbuf,
    const ushort* __restrict__ vfrag, const ushort* __restrict__ btf,
    const float* __restrict__ c1b, const float* __restrict__ c3b,
    const float* __restrict__ c5b,
    const float* __restrict__ mbuf, ushort* __restrict__ attn)
{
    __shared__ __align__(16) char pool[40960];
    char* SC  = pool;                       // scores bf16 [80][512B], swizzled
    char* PB  = pool;                       // P bf16 [64][512B] (aliases SC)
    float* RED = (float*)(pool + 37888);    // [64][4] (SC rows 74+, unused by conv)

    const int tid  = threadIdx.x;
    const int lane = tid & 63;
    const int w    = tid >> 6;
    const int l15  = lane & 15, l4 = lane >> 4;
    const int head = blockIdx.y;            // b*H + h
    const int bb   = head >> 3, hh = head & 7;
    const int i0   = blockIdx.x * 64;
    const int cb   = w * 64;                // this wave's column base

    // ---- phase 1: scores rows i0-8 .. i0+71 (80 rows), unscaled ----
    {
        const ushort* kb_h = kbuf + (size_t)head * S * DH;
        const ushort* qb_h = q    + (size_t)head * S * DH;
        f32x4 sacc[5][4];
        #pragma unroll
        for (int rt = 0; rt < 5; ++rt)
            #pragma unroll
            for (int n = 0; n < 4; ++n)
                sacc[rt][n] = (f32x4){0.f, 0.f, 0.f, 0.f};

        #pragma unroll
        for (int kk = 0; kk < 2; ++kk) {
            s16x8 bfr[4];
            #pragma unroll
            for (int n = 0; n < 4; ++n)
                bfr[n] = *(const s16x8*)(kb_h
                         + (size_t)(cb + n * 16 + l15) * 64 + kk * 32 + 8 * l4);
            #pragma unroll
            for (int rt = 0; rt < 5; ++rt) {
                const int qrow = i0 - 8 + rt * 16 + l15;
                s16x8 afr = (s16x8){0,0,0,0,0,0,0,0};
                if ((unsigned)qrow < (unsigned)S)
                    afr = *(const s16x8*)(qb_h + (size_t)qrow * 64 + kk * 32 + 8 * l4);
                #pragma unroll
                for (int n = 0; n < 4; ++n)
                    sacc[rt][n] = __builtin_amdgcn_mfma_f32_16x16x32_bf16(
                                      afr, bfr[n], sacc[rt][n], 0, 0, 0);
            }
        }
        #pragma unroll
        for (int rt = 0; rt < 5; ++rt)
            #pragma unroll
            for (int n = 0; n < 4; ++n)
                #pragma unroll
                for (int rg = 0; rg < 4; ++rg) {
                    const int srow = rt * 16 + l4 * 4 + rg;
                    const int col  = cb + n * 16 + l15;
                    const int byt  = (srow * 512 + col * 2) ^ ((srow & 7) << 4);
                    *(short*)(SC + byt) = f2bf(sacc[rt][n][rg]);
                }
    }
    __syncthreads();

    // ---- phase 2: Toeplitz conv; coalesced btf loads, depth-2 prefetch ----
    f32x4 cacc[4][4];
    #pragma unroll
    for (int rt = 0; rt < 4; ++rt)
        #pragma unroll
        for (int n = 0; n < 4; ++n)
            cacc[rt][n] = (f32x4){0.f, 0.f, 0.f, 0.f};

    {
        const ushort* btw = btf + (size_t)(w * 4) * 40 * 512 + lane * 8;

        s16x8 pb[4][4];
        auto ldB = [&](int st, int slot) {
            #pragma unroll
            for (int i = 0; i < 4; ++i)
                pb[slot][i] = *(const s16x8*)(btw + (size_t)(i * 40 + st) * 512);
        };
        auto convStep = [&](int st, int slot) {
            const int r = st >> 3, kb2 = (st & 7) * 64 + 16 * l4;
            #pragma unroll
            for (int rt = 0; rt < 4; ++rt) {
                const int sr = rt * 16 + l15 + r + 6;
                const s16x8 afr = *(const s16x8*)(SC + ((sr * 512 + kb2) ^ ((sr & 7) << 4)));
                #pragma unroll
                for (int n = 0; n < 4; ++n)
                    cacc[rt][n] = __builtin_amdgcn_mfma_f32_16x16x32_bf16(
                                      afr, pb[slot][n], cacc[rt][n], 0, 0, 0);
            }
        };

        ldB(0, 0); ldB(1, 1);
        for (int qq = 0; qq < 10; ++qq) {
            const int st = qq * 4;
            ldB(st + 2, 2);
            convStep(st + 0, 0);
            ldB(st + 3, 3);
            convStep(st + 1, 1);
            if (st + 4 < 40) ldB(st + 4, 0);
            convStep(st + 2, 2);
            if (st + 5 < 40) ldB(st + 5, 1);
            convStep(st + 3, 3);
        }
    }

    // ---- phase 2.5: + combined bias + m ----
    {
        const float bias_comb = (c1b[0] + c3b[0] + c5b[0]) * (1.f / 3.f);
        const float* mrow = mbuf + (size_t)bb * 65536;
        #pragma unroll
        for (int rt = 0; rt < 4; ++rt)
            #pragma unroll
            for (int rg = 0; rg < 4; ++rg) {
                const int i = i0 + rt * 16 + l4 * 4 + rg;
                #pragma unroll
                for (int n = 0; n < 4; ++n) {
                    const int j = cb + n * 16 + l15;
                    cacc[rt][n][rg] += bias_comb + mrow[i * 256 + j];
                }
            }
    }

    // ---- phase 3: softmax ----
    float rmax[4][4];
    #pragma unroll
    for (int rt = 0; rt < 4; ++rt)
        #pragma unroll
        for (int rg = 0; rg < 4; ++rg) {
            float mx = fmaxf(fmaxf(cacc[rt][0][rg], cacc[rt][1][rg]),
                             fmaxf(cacc[rt][2][rg], cacc[rt][3][rg]));
            mx = fmaxf(mx, __shfl_xor(mx, 1));
            mx = fmaxf(mx, __shfl_xor(mx, 2));
            mx = fmaxf(mx, __shfl_xor(mx, 4));
            mx = fmaxf(mx, __shfl_xor(mx, 8));
            rmax[rt][rg] = mx;
        }
    if (l15 == 0) {
        #pragma unroll
        for (int rt = 0; rt < 4; ++rt)
            #pragma unroll
            for (int rg = 0; rg < 4; ++rg)
                RED[(rt * 16 + l4 * 4 + rg) * 4 + w] = rmax[rt][rg];
    }
    __syncthreads();
    #pragma unroll
    for (int rt = 0; rt < 4; ++rt)
        #pragma unroll
        for (int rg = 0; rg < 4; ++rg) {
            const int row = rt * 16 + l4 * 4 + rg;
            rmax[rt][rg] = fmaxf(fmaxf(RED[row * 4 + 0], RED[row * 4 + 1]),
                                 fmaxf(RED[row * 4 + 2], RED[row * 4 + 3]));
        }
    __syncthreads();

    float rinv[4][4];
    #pragma unroll
    for (int rt = 0; rt < 4; ++rt)
        #pragma unroll
        for (int rg = 0; rg < 4; ++rg) {
            float sm = 0.f;
            #pragma unroll
            for (int n = 0; n < 4; ++n) {
                const float e = __expf(cacc[rt][n][rg] - rmax[rt][rg]);
                cacc[rt][n][rg] = e;
                sm += e;
            }
            sm += __shfl_xor(sm, 1);
            sm += __shfl_xor(sm, 2);
            sm += __shfl_xor(sm, 4);
            sm += __shfl_xor(sm, 8);
            rinv[rt][rg] = sm;
        }
    if (l15 == 0) {
        #pragma unroll
        for (int rt = 0; rt < 4; ++rt)
            #pragma unroll
            for (int rg = 0; rg < 4; ++rg)
                RED[(rt * 16 + l4 * 4 + rg) * 4 + w] = rinv[rt][rg];
    }
    __syncthreads();
    #pragma unroll
    for (int rt = 0; rt < 4; ++rt)
        #pragma unroll
        for (int rg = 0; rg < 4; ++rg) {
            const int row = rt * 16 + l4 * 4 + rg;
            const float tot = (RED[row * 4 + 0] + RED[row * 4 + 1])
                            + (RED[row * 4 + 2] + RED[row * 4 + 3]);
            rinv[rt][rg] = 1.f / tot;
        }
    __syncthreads();   // conv SC-reads & RED reads done before PB overwrite

    // ---- write P (bf16, swizzled, aliases SC rows 0-63) ----
    #pragma unroll
    for (int rt = 0; rt < 4; ++rt)
        #pragma unroll
        for (int n = 0; n < 4; ++n)
            #pragma unroll
            for (int rg = 0; rg < 4; ++rg) {
                const int row = rt * 16 + l4 * 4 + rg;
                const int col = cb + n * 16 + l15;
                const int byt = (row * 512 + col * 2) ^ ((row & 7) << 4);
                *(short*)(PB + byt) = f2bf(cacc[rt][n][rg] * rinv[rt][rg]);
            }
    __syncthreads();

    // ---- phase 4: PV via MFMA; B-frags coalesced from vfrag ----
    const ushort* vf_h = vfrag + (size_t)head * 4 * 8 * 512 + lane * 8;
    f32x4 pacc[4];
    #pragma unroll
    for (int n = 0; n < 4; ++n) pacc[n] = (f32x4){0.f, 0.f, 0.f, 0.f};
    #pragma unroll
    for (int kk = 0; kk < 8; ++kk) {
        const int prow = w * 16 + l15;
        const int byta = (prow * 512 + kk * 64 + 16 * l4) ^ ((prow & 7) << 4);
        const s16x8 pa = *(const s16x8*)(PB + byta);
        #pragma unroll
        for (int n = 0; n < 4; ++n) {
            const s16x8 vb8 = *(const s16x8*)(vf_h + (size_t)(n * 8 + kk) * 512);
            pacc[n] = __builtin_amdgcn_mfma_f32_16x16x32_bf16(pa, vb8, pacc[n], 0, 0, 0);
        }
    }
    #pragma unroll
    for (int n = 0; n < 4; ++n)
        #pragma unroll
        for (int rg = 0; rg < 4; ++rg) {
            const int i = i0 + w * 16 + l4 * 4 + rg;
            const int d = n * 16 + l15;
            attn[(((size_t)bb * S + i) * H + hh) * DH + d] = (ushort)f2bf(pacc[n][rg]);
        }
}

// ---------------------------------------------------------------------------
// launcher
// ---------------------------------------------------------------------------
extern "C" void kernel_launch(void* const* d_in, const int* in_sizes, int n_in,
                              void* d_out, int out_size, void* d_ws, size_t ws_size,
                              hipStream_t stream)
{
    (void)in_sizes; (void)n_in; (void)out_size; (void)ws_size;

    const float* x        = (const float*)d_in[0];
    const float* particles= (const float*)d_in[1];
    const float* wq       = (const float*)d_in[2];
    const float* wk       = (const float*)d_in[3];
    const float* wv       = (const float*)d_in[4];
    const float* dense_w  = (const float*)d_in[5];
    const float* dense_b  = (const float*)d_in[6];
    const float* c1k      = (const float*)d_in[7];
    const float* c1b      = (const float*)d_in[8];
    const float* c3k      = (const float*)d_in[9];
    const float* c3b      = (const float*)d_in[10];
    const float* c5k      = (const float*)d_in[11];
    const float* c5b      = (const float*)d_in[12];
    const float* mw1      = (const float*)d_in[13];
    const float* mb1      = (const float*)d_in[14];
    const float* mw2      = (const float*)d_in[15];
    const float* mb2      = (const float*)d_in[16];
    const float* mw3      = (const float*)d_in[17];
    const float* mb3      = (const float*)d_in[18];
    float* out = (float*)d_out;

    // workspace layout (ushort units unless noted), total ~120 MB
    ushort* xbf   = (ushort*)d_ws;                       //  8,388,608
    ushort* wt    = xbf   + (size_t)8388608;             //  1,048,576
    ushort* qb    = wt    + (size_t)1048576;             //  8,388,608
    ushort* kb    = qb    + (size_t)8388608;             //  8,388,608
    ushort* vbT   = kb    + (size_t)8388608;             //  8,388,608  [BH][DH][S]
    ushort* attnb = vbT   + (size_t)8388608;             //  8,388,608
    ushort* btf   = attnb + (size_t)8388608;             //    327,680  frag-linear
    ushort* vfrag = btf   + (size_t)327680;              //  8,388,608  frag-linear
    float*  mb    = (float*)(vfrag + (size_t)8388608);   //  4,194,304 f32

    convert_x_kernel<<<dim3(4096), 256, 0, stream>>>(x, xbf);
    transpose_w_kernel<<<dim3(16, 16, 4), 256, 0, stream>>>(wq, wk, wv, dense_w, wt);
    build_toeplitz_frag_kernel<<<dim3(160), 256, 0, stream>>>(c1k, c3k, c5k, btf);
    pairwise_mlp_kernel<<<dim3(B * S), 256, 0, stream>>>(particles, mw1, mb1, mw2, mb2, mw3, mb3, mb);

    gemm_mfma_kernel<0><<<dim3(4, 128, 3), 256, 0, stream>>>(
        xbf, wt, qb, kb, vbT, nullptr, nullptr);
    vfrag_repack_kernel<<<dim3(4096), 256, 0, stream>>>(vbT, vfrag);

    fused_mfma_kernel<<<dim3(4, BH), 256, 0, stream>>>(
        qb, kb, vfrag, btf, c1b, c3b, c5b, mb, attnb);

    gemm_mfma_kernel<1><<<dim3(4, 128, 1), 256, 0, stream>>>(
        attnb, wt + (size_t)3 * DD * DD, nullptr, nullptr, nullptr, dense_b, out);
}

// Round 7
// 310.906 us; speedup vs baseline: 1.2688x; 1.0646x over previous
//
#include <hip/hip_runtime.h>
#include <hip/hip_bf16.h>
#include <math.h>

// Problem constants
#define B   64
#define S   256
#define DD  512
#define H   8
#define DH  64
#define BH  (B*H)   // 512

typedef short s16x8 __attribute__((ext_vector_type(8)));
typedef short s16x4 __attribute__((ext_vector_type(4)));
typedef float f32x4 __attribute__((ext_vector_type(4)));

typedef __attribute__((address_space(3))) unsigned int       lds_u32;
typedef __attribute__((address_space(1))) const unsigned int glb_u32;

__device__ __forceinline__ short f2bf(float f) {
    union { float f; unsigned u; } v; v.f = f;
    unsigned u = v.u;
    u += 0x7FFFu + ((u >> 16) & 1u);   // RNE
    return (short)(u >> 16);
}

__device__ __forceinline__ void glds16(const void* g, void* l) {
    __builtin_amdgcn_global_load_lds((glb_u32*)g, (lds_u32*)l, 16, 0, 0);
}

// ---------------------------------------------------------------------------
// P1: x (f32, 16384x512) -> xbf (bf16)
// ---------------------------------------------------------------------------
__global__ __launch_bounds__(256) void convert_x_kernel(
    const float* __restrict__ x, ushort* __restrict__ xbf)
{
    const int idx = blockIdx.x * 256 + threadIdx.x;
    const float4 f0 = *(const float4*)(x + (size_t)idx * 8);
    const float4 f1 = *(const float4*)(x + (size_t)idx * 8 + 4);
    s16x8 o = { f2bf(f0.x), f2bf(f0.y), f2bf(f0.z), f2bf(f0.w),
                f2bf(f1.x), f2bf(f1.y), f2bf(f1.z), f2bf(f1.w) };
    *(s16x8*)(xbf + (size_t)idx * 8) = o;
}

// ---------------------------------------------------------------------------
// P2: transpose+convert weights: wt[z][n][k] = w_z[k][n]  (bf16)
// ---------------------------------------------------------------------------
__global__ __launch_bounds__(256) void transpose_w_kernel(
    const float* __restrict__ wq, const float* __restrict__ wk,
    const float* __restrict__ wv, const float* __restrict__ wd,
    ushort* __restrict__ wt)
{
    __shared__ float tile[32][33];
    const int z = blockIdx.z;
    const float* w = (z == 0) ? wq : (z == 1) ? wk : (z == 2) ? wv : wd;
    const int k0 = blockIdx.y * 32, n0 = blockIdx.x * 32;
    const int tx = threadIdx.x & 31, ty = threadIdx.x >> 5;

    #pragma unroll
    for (int r = 0; r < 32; r += 8)
        tile[ty + r][tx] = w[(size_t)(k0 + ty + r) * DD + n0 + tx];
    __syncthreads();
    #pragma unroll
    for (int r = 0; r < 32; r += 8)
        wt[(size_t)z * DD * DD + (size_t)(n0 + ty + r) * DD + k0 + tx] =
            (ushort)f2bf(tile[tx][ty + r]);
}

// ---------------------------------------------------------------------------
// P2b: Toeplitz B in MFMA-fragment-linear order:
//   btf[((n*40 + st)*64 + lane)*8 + e] = kcomb[r][t - c + 127] / 24
//   c = n*16 + (lane&15), r = st>>3, t = (st&7)*32 + (lane>>4)*8 + e.
// ---------------------------------------------------------------------------
__global__ __launch_bounds__(256) void build_toeplitz_frag_kernel(
    const float* __restrict__ c1k, const float* __restrict__ c3k,
    const float* __restrict__ c5k, ushort* __restrict__ btf)
{
    const int idx  = blockIdx.x * 256 + threadIdx.x;   // 0..40959
    const int lane = idx & 63;
    const int st   = (idx >> 6) % 40;
    const int n    = idx / (40 * 64);
    const int c    = n * 16 + (lane & 15);
    const int r    = st >> 3;
    const int tb   = (st & 7) * 32 + (lane >> 4) * 8;

    s16x8 o;
    #pragma unroll
    for (int e = 0; e < 8; ++e) {
        const int ki = tb + e - c + 127;
        float val = 0.f;
        if (ki >= 0 && ki < 256) {
            val = c5k[r * 256 + ki];
            if (r >= 1 && r <= 3) val += c3k[(r - 1) * 256 + ki];
            if (r == 2)           val += c1k[ki];
            val *= (1.f / 24.f);
        }
        o[e] = f2bf(val);
    }
    *(s16x8*)(btf + (size_t)idx * 8) = o;
}

// ---------------------------------------------------------------------------
// P2c: repack vbT -> PV-fragment-linear vfrag
// ---------------------------------------------------------------------------
__global__ __launch_bounds__(256) void vfrag_repack_kernel(
    const ushort* __restrict__ vbT, ushort* __restrict__ vfrag)
{
    const int idx  = blockIdx.x * 256 + threadIdx.x;   // 0..1048575
    const int lane = idx & 63;
    const int kk   = (idx >> 6) & 7;
    const int n    = (idx >> 9) & 3;
    const int head = idx >> 11;
    const s16x8 v = *(const s16x8*)(vbT
        + ((size_t)(head * 64 + n * 16 + (lane & 15))) * 256
        + kk * 32 + (lane >> 4) * 8);
    *(s16x8*)(vfrag + (size_t)idx * 8) = v;
}

// ---------------------------------------------------------------------------
// P3: bf16 MFMA GEMM, 128x128 tile, BK=64, 4 waves (2x2), m97 structure.
// MODE 0: qkv. z=0 -> q; z=1 -> k; z=2 -> V transposed vbT[(bh*DH+dd)*S+ss]
// MODE 1: dense -> f32 out = acc + bias[col].
// ---------------------------------------------------------------------------
template<int MODE>
__global__ __launch_bounds__(256) void gemm_mfma_kernel(
    const ushort* __restrict__ A, const ushort* __restrict__ BtAll,
    ushort* __restrict__ qo, ushort* __restrict__ ko, ushort* __restrict__ vo,
    const float* __restrict__ bias, float* __restrict__ outf)
{
    __shared__ ushort As[128 * 64];
    __shared__ ushort Bs[128 * 64];

    const int tid  = threadIdx.x;
    const int lane = tid & 63, w = tid >> 6;
    const int l15  = lane & 15, l4 = lane >> 4;
    const int wr   = w >> 1, wc = w & 1;
    const int row0 = blockIdx.y * 128, col0 = blockIdx.x * 128;
    const ushort* Bt = BtAll + (MODE == 0 ? (size_t)blockIdx.z * DD * DD : 0);

    f32x4 acc[4][4];
    #pragma unroll
    for (int mt = 0; mt < 4; ++mt)
        #pragma unroll
        for (int nt = 0; nt < 4; ++nt)
            acc[mt][nt] = (f32x4){0.f, 0.f, 0.f, 0.f};

    const int arow = tid >> 3;
    const int acol = (tid & 7) * 8;
    char* ldsA = (char*)As + (tid >> 6) * 1024;
    char* ldsB = (char*)Bs + (tid >> 6) * 1024;

    for (int k0 = 0; k0 < DD; k0 += 64) {
        #pragma unroll
        for (int i = 0; i < 4; ++i)
            glds16(A  + (size_t)(row0 + arow + 32 * i) * DD + k0 + acol,
                   ldsA + 4096 * i);
        #pragma unroll
        for (int i = 0; i < 4; ++i)
            glds16(Bt + (size_t)(col0 + arow + 32 * i) * DD + k0 + acol,
                   ldsB + 4096 * i);
        __syncthreads();

        #pragma unroll
        for (int kk = 0; kk < 2; ++kk) {
            s16x8 af[4], bf[4];
            #pragma unroll
            for (int mt = 0; mt < 4; ++mt) {
                const int row = wr * 64 + mt * 16 + l15;
                af[mt] = *(const s16x8*)((char*)As + row * 128 + kk * 64 + l4 * 16);
            }
            #pragma unroll
            for (int nt = 0; nt < 4; ++nt) {
                const int col = wc * 64 + nt * 16 + l15;
                bf[nt] = *(const s16x8*)((char*)Bs + col * 128 + kk * 64 + l4 * 16);
            }
            #pragma unroll
            for (int mt = 0; mt < 4; ++mt)
                #pragma unroll
                for (int nt = 0; nt < 4; ++nt)
                    acc[mt][nt] = __builtin_amdgcn_mfma_f32_16x16x32_bf16(
                                      af[mt], bf[nt], acc[mt][nt], 0, 0, 0);
        }
        __syncthreads();
    }

    if (MODE == 0) {
        if (blockIdx.z == 2) {
            #pragma unroll
            for (int mt = 0; mt < 4; ++mt)
                #pragma unroll
                for (int nt = 0; nt < 4; ++nt) {
                    const int r = row0 + wr * 64 + mt * 16 + l4 * 4;
                    const int c = col0 + wc * 64 + nt * 16 + l15;
                    const int bb = r >> 8, ss = r & 255;
                    const int hh = c >> 6, dd = c & 63;
                    s16x4 pk = { f2bf(acc[mt][nt][0]), f2bf(acc[mt][nt][1]),
                                 f2bf(acc[mt][nt][2]), f2bf(acc[mt][nt][3]) };
                    *(s16x4*)(vo + ((size_t)((bb * H + hh) * DH + dd)) * S + ss) = pk;
                }
        } else {
            ushort* dst = (blockIdx.z == 0) ? qo : ko;
            #pragma unroll
            for (int mt = 0; mt < 4; ++mt)
                #pragma unroll
                for (int nt = 0; nt < 4; ++nt)
                    #pragma unroll
                    for (int rg = 0; rg < 4; ++rg) {
                        const int r = row0 + wr * 64 + mt * 16 + l4 * 4 + rg;
                        const int c = col0 + wc * 64 + nt * 16 + l15;
                        const int bb = r >> 8, ss = r & 255;
                        const int hh = c >> 6, dd = c & 63;
                        dst[(((size_t)(bb * H + hh)) * S + ss) * DH + dd] =
                            (ushort)f2bf(acc[mt][nt][rg]);
                    }
        }
    } else {
        #pragma unroll
        for (int mt = 0; mt < 4; ++mt)
            #pragma unroll
            for (int nt = 0; nt < 4; ++nt)
                #pragma unroll
                for (int rg = 0; rg < 4; ++rg) {
                    const int r = row0 + wr * 64 + mt * 16 + l4 * 4 + rg;
                    const int c = col0 + wc * 64 + nt * 16 + l15;
                    outf[(size_t)r * DD + c] = acc[mt][nt][rg] + bias[c];
                }
    }
}

// ---------------------------------------------------------------------------
// K2: pairwise features + tiny MLP.  Writes m DIRECTLY in the fused kernel's
// fragment-linear layout (f32, bias_comb folded in):
//   mfrag[(((b*4+chunk)*4 + wave)*64 + lane)*64 + rt*16 + n*4 + rg]
// where i = chunk*64 + rt*16 + (lane>>4)*4 + rg,  j = wave*64 + n*16 + (lane&15)
// ---------------------------------------------------------------------------
__global__ __launch_bounds__(256) void pairwise_mlp_kernel(
    const float* __restrict__ particles,
    const float* __restrict__ mw1, const float* __restrict__ mb1,
    const float* __restrict__ mw2, const float* __restrict__ mb2,
    const float* __restrict__ mw3, const float* __restrict__ mb3,
    const float* __restrict__ c1b, const float* __restrict__ c3b,
    const float* __restrict__ c5b,
    float* __restrict__ mfrag)
{
    __shared__ float w1[32], b1[8], w2[64], b2[8], w3[8];
    __shared__ float b3s;
    const int tid = threadIdx.x;
    if (tid < 32)                 w1[tid]        = mw1[tid];
    if (tid >= 32 && tid < 40)    b1[tid - 32]   = mb1[tid - 32];
    if (tid >= 64 && tid < 128)   w2[tid - 64]   = mw2[tid - 64];
    if (tid >= 128 && tid < 136)  b2[tid - 128]  = mb2[tid - 128];
    if (tid >= 136 && tid < 144)  w3[tid - 136]  = mw3[tid - 136];
    if (tid == 144)               b3s            = mb3[0];

    const int bi = blockIdx.x;            // b*S + i
    const int bb = bi >> 8;
    const float pt_i  = particles[(size_t)bi * 3 + 0];
    const float eta_i = particles[(size_t)bi * 3 + 1];
    const float phi_i = particles[(size_t)bi * 3 + 2];

    const int j = tid;
    const float* pj = particles + ((size_t)(bb * S) + j) * 3;
    const float pt_j = pj[0], eta_j = pj[1], phi_j = pj[2];

    __syncthreads();

    const float d_eta = eta_i - eta_j;
    const float dp    = phi_i - phi_j;
    const float d_phi = atan2f(sinf(dp), cosf(dp));
    const float delta = sqrtf(d_eta * d_eta + d_phi * d_phi);
    const float min_pt = fminf(pt_i, pt_j);
    const float kT = min_pt * delta;
    const float zf = min_pt / (pt_i + pt_j + 1e-8f);
    const float cd = cosf(d_phi);
    const float m2 = fmaxf(pt_i * pt_i + pt_j * pt_j - 2.0f * pt_i * pt_j * cd, 1e-8f);

    const float eps = 1e-8f;
    const float f[4] = { logf(fmaxf(delta, eps)),
                         logf(fmaxf(kT,    eps)),
                         logf(fmaxf(zf,    eps)),
                         logf(m2) };

    float h1[8];
    #pragma unroll
    for (int o = 0; o < 8; ++o) {
        float s = b1[o];
        #pragma unroll
        for (int i4 = 0; i4 < 4; ++i4) s += f[i4] * w1[i4 * 8 + o];
        h1[o] = fmaxf(s, 0.0f);
    }
    float h2[8];
    #pragma unroll
    for (int o = 0; o < 8; ++o) {
        float s = b2[o];
        #pragma unroll
        for (int i8 = 0; i8 < 8; ++i8) s += h1[i8] * w2[i8 * 8 + o];
        h2[o] = fmaxf(s, 0.0f);
    }
    float mv = b3s;
    #pragma unroll
    for (int i8 = 0; i8 < 8; ++i8) mv += h2[i8] * w3[i8];
    mv = fminf(fmaxf(mv, -10.0f), 10.0f);
    mv += (c1b[0] + c3b[0] + c5b[0]) * (1.f / 3.f);   // fold conv bias

    // scatter into fragment-linear layout
    const int ii    = bi & 255;
    const int chunk = ii >> 6, rt = (ii >> 4) & 3, l4h = (ii >> 2) & 3, rg = ii & 3;
    const int wv2   = j >> 6,  n2 = (j >> 4) & 3,  l15 = j & 15;
    const int lane  = l4h * 16 + l15;
    mfrag[((((size_t)(bb * 4 + chunk)) * 4 + wv2) * 64 + lane) * 64
          + rt * 16 + n2 * 4 + rg] = mv;
}

// ---------------------------------------------------------------------------
// K3: MFMA-fused  scores -> Toeplitz conv -> +m -> softmax -> PV
// Phase 1 uses SWAPPED operands (A=K, B=Q) so the C-fragment's 4 regs run
// along t -> SC writes are ds_write_b64 (20/thread, ~2-way = free).
// m added from mfrag (fragment-linear, 16 x b128 coalesced loads).
// LDS = 40 KB: SC [80][512B] swizzled; RED in SC rows 74+; PB aliases SC.
// ---------------------------------------------------------------------------
__global__ __launch_bounds__(256, 4) void fused_mfma_kernel(
    const ushort* __restrict__ q, const ushort* __restrict__ kbuf,
    const ushort* __restrict__ vfrag, const ushort* __restrict__ btf,
    const float* __restrict__ mfrag, ushort* __restrict__ attn)
{
    __shared__ __align__(16) char pool[40960];
    char* SC  = pool;                       // scores bf16 [80][512B], swizzled
    char* PB  = pool;                       // P bf16 [64][512B] (aliases SC)
    float* RED = (float*)(pool + 37888);    // [64][4] (SC rows 74+, unused by conv)

    const int tid  = threadIdx.x;
    const int lane = tid & 63;
    const int w    = tid >> 6;
    const int l15  = lane & 15, l4 = lane >> 4;
    const int head = blockIdx.y;            // b*H + h
    const int bb   = head >> 3, hh = head & 7;
    const int i0   = blockIdx.x * 64;
    const int cb   = w * 64;                // this wave's column base

    // ---- phase 1 (swapped): S^tile = K(A) x Q(B); C: m=t, n=i ----
    {
        const ushort* kb_h = kbuf + (size_t)head * S * DH;
        const ushort* qb_h = q    + (size_t)head * S * DH;
        f32x4 sacc[4][5];
        #pragma unroll
        for (int mt = 0; mt < 4; ++mt)
            #pragma unroll
            for (int nt = 0; nt < 5; ++nt)
                sacc[mt][nt] = (f32x4){0.f, 0.f, 0.f, 0.f};

        #pragma unroll
        for (int kk = 0; kk < 2; ++kk) {
            s16x8 afr[4];
            #pragma unroll
            for (int mt = 0; mt < 4; ++mt)
                afr[mt] = *(const s16x8*)(kb_h
                          + (size_t)(cb + mt * 16 + l15) * 64 + kk * 32 + 8 * l4);
            #pragma unroll
            for (int nt = 0; nt < 5; ++nt) {
                const int qrow = i0 - 8 + nt * 16 + l15;
                s16x8 bfr = (s16x8){0,0,0,0,0,0,0,0};
                if ((unsigned)qrow < (unsigned)S)
                    bfr = *(const s16x8*)(qb_h + (size_t)qrow * 64 + kk * 32 + 8 * l4);
                #pragma unroll
                for (int mt = 0; mt < 4; ++mt)
                    sacc[mt][nt] = __builtin_amdgcn_mfma_f32_16x16x32_bf16(
                                       afr[mt], bfr, sacc[mt][nt], 0, 0, 0);
            }
        }
        // write SC[i][t], 4 consecutive t per b64
        #pragma unroll
        for (int mt = 0; mt < 4; ++mt)
            #pragma unroll
            for (int nt = 0; nt < 5; ++nt) {
                const int i  = nt * 16 + l15;          // SC row (rel)
                const int t0 = cb + mt * 16 + l4 * 4;  // col base
                s16x4 pk = { f2bf(sacc[mt][nt][0]), f2bf(sacc[mt][nt][1]),
                             f2bf(sacc[mt][nt][2]), f2bf(sacc[mt][nt][3]) };
                const int byt = (i * 512 + t0 * 2) ^ ((i & 7) << 4);
                *(s16x4*)(SC + byt) = pk;
            }
    }
    __syncthreads();

    // ---- phase 2: Toeplitz conv; coalesced btf loads, 4-slot prefetch ----
    f32x4 cacc[4][4];
    #pragma unroll
    for (int rt = 0; rt < 4; ++rt)
        #pragma unroll
        for (int n = 0; n < 4; ++n)
            cacc[rt][n] = (f32x4){0.f, 0.f, 0.f, 0.f};

    {
        const ushort* btw = btf + (size_t)(w * 4) * 40 * 512 + lane * 8;

        s16x8 pb[4][4];
        auto ldB = [&](int st, int slot) {
            #pragma unroll
            for (int i = 0; i < 4; ++i)
                pb[slot][i] = *(const s16x8*)(btw + (size_t)(i * 40 + st) * 512);
        };
        auto convStep = [&](int st, int slot) {
            const int r = st >> 3, kb2 = (st & 7) * 64 + 16 * l4;
            #pragma unroll
            for (int rt = 0; rt < 4; ++rt) {
                const int sr = rt * 16 + l15 + r + 6;
                const s16x8 afr = *(const s16x8*)(SC + ((sr * 512 + kb2) ^ ((sr & 7) << 4)));
                #pragma unroll
                for (int n = 0; n < 4; ++n)
                    cacc[rt][n] = __builtin_amdgcn_mfma_f32_16x16x32_bf16(
                                      afr, pb[slot][n], cacc[rt][n], 0, 0, 0);
            }
        };

        ldB(0, 0); ldB(1, 1);
        for (int qq = 0; qq < 10; ++qq) {
            const int st = qq * 4;
            ldB(st + 2, 2);
            convStep(st + 0, 0);
            ldB(st + 3, 3);
            convStep(st + 1, 1);
            if (st + 4 < 40) ldB(st + 4, 0);
            convStep(st + 2, 2);
            if (st + 5 < 40) ldB(st + 5, 1);
            convStep(st + 3, 3);
        }
    }

    // ---- phase 2.5: + m (fragment-linear, coalesced b128) ----
    {
        const float* mf = mfrag
            + ((((size_t)(bb * 4 + blockIdx.x)) * 4 + w) * 64 + lane) * 64;
        #pragma unroll
        for (int rt = 0; rt < 4; ++rt)
            #pragma unroll
            for (int n = 0; n < 4; ++n) {
                const float4 mv = *(const float4*)(mf + rt * 16 + n * 4);
                cacc[rt][n][0] += mv.x;
                cacc[rt][n][1] += mv.y;
                cacc[rt][n][2] += mv.z;
                cacc[rt][n][3] += mv.w;
            }
    }

    // ---- phase 3: softmax ----
    float rmax[4][4];
    #pragma unroll
    for (int rt = 0; rt < 4; ++rt)
        #pragma unroll
        for (int rg = 0; rg < 4; ++rg) {
            float mx = fmaxf(fmaxf(cacc[rt][0][rg], cacc[rt][1][rg]),
                             fmaxf(cacc[rt][2][rg], cacc[rt][3][rg]));
            mx = fmaxf(mx, __shfl_xor(mx, 1));
            mx = fmaxf(mx, __shfl_xor(mx, 2));
            mx = fmaxf(mx, __shfl_xor(mx, 4));
            mx = fmaxf(mx, __shfl_xor(mx, 8));
            rmax[rt][rg] = mx;
        }
    if (l15 == 0) {
        #pragma unroll
        for (int rt = 0; rt < 4; ++rt)
            #pragma unroll
            for (int rg = 0; rg < 4; ++rg)
                RED[(rt * 16 + l4 * 4 + rg) * 4 + w] = rmax[rt][rg];
    }
    __syncthreads();
    #pragma unroll
    for (int rt = 0; rt < 4; ++rt)
        #pragma unroll
        for (int rg = 0; rg < 4; ++rg) {
            const int row = rt * 16 + l4 * 4 + rg;
            rmax[rt][rg] = fmaxf(fmaxf(RED[row * 4 + 0], RED[row * 4 + 1]),
                                 fmaxf(RED[row * 4 + 2], RED[row * 4 + 3]));
        }
    __syncthreads();

    float rinv[4][4];
    #pragma unroll
    for (int rt = 0; rt < 4; ++rt)
        #pragma unroll
        for (int rg = 0; rg < 4; ++rg) {
            float sm = 0.f;
            #pragma unroll
            for (int n = 0; n < 4; ++n) {
                const float e = __expf(cacc[rt][n][rg] - rmax[rt][rg]);
                cacc[rt][n][rg] = e;
                sm += e;
            }
            sm += __shfl_xor(sm, 1);
            sm += __shfl_xor(sm, 2);
            sm += __shfl_xor(sm, 4);
            sm += __shfl_xor(sm, 8);
            rinv[rt][rg] = sm;
        }
    if (l15 == 0) {
        #pragma unroll
        for (int rt = 0; rt < 4; ++rt)
            #pragma unroll
            for (int rg = 0; rg < 4; ++rg)
                RED[(rt * 16 + l4 * 4 + rg) * 4 + w] = rinv[rt][rg];
    }
    __syncthreads();
    #pragma unroll
    for (int rt = 0; rt < 4; ++rt)
        #pragma unroll
        for (int rg = 0; rg < 4; ++rg) {
            const int row = rt * 16 + l4 * 4 + rg;
            const float tot = (RED[row * 4 + 0] + RED[row * 4 + 1])
                            + (RED[row * 4 + 2] + RED[row * 4 + 3]);
            rinv[rt][rg] = 1.f / tot;
        }
    __syncthreads();   // conv SC-reads & RED reads done before PB overwrite

    // ---- write P (bf16, swizzled, aliases SC rows 0-63) ----
    #pragma unroll
    for (int rt = 0; rt < 4; ++rt)
        #pragma unroll
        for (int n = 0; n < 4; ++n)
            #pragma unroll
            for (int rg = 0; rg < 4; ++rg) {
                const int row = rt * 16 + l4 * 4 + rg;
                const int col = cb + n * 16 + l15;
                const int byt = (row * 512 + col * 2) ^ ((row & 7) << 4);
                *(short*)(PB + byt) = f2bf(cacc[rt][n][rg] * rinv[rt][rg]);
            }
    __syncthreads();

    // ---- phase 4: PV via MFMA; B-frags coalesced from vfrag ----
    const ushort* vf_h = vfrag + (size_t)head * 4 * 8 * 512 + lane * 8;
    f32x4 pacc[4];
    #pragma unroll
    for (int n = 0; n < 4; ++n) pacc[n] = (f32x4){0.f, 0.f, 0.f, 0.f};
    #pragma unroll
    for (int kk = 0; kk < 8; ++kk) {
        const int prow = w * 16 + l15;
        const int byta = (prow * 512 + kk * 64 + 16 * l4) ^ ((prow & 7) << 4);
        const s16x8 pa = *(const s16x8*)(PB + byta);
        #pragma unroll
        for (int n = 0; n < 4; ++n) {
            const s16x8 vb8 = *(const s16x8*)(vf_h + (size_t)(n * 8 + kk) * 512);
            pacc[n] = __builtin_amdgcn_mfma_f32_16x16x32_bf16(pa, vb8, pacc[n], 0, 0, 0);
        }
    }
    #pragma unroll
    for (int n = 0; n < 4; ++n)
        #pragma unroll
        for (int rg = 0; rg < 4; ++rg) {
            const int i = i0 + w * 16 + l4 * 4 + rg;
            const int d = n * 16 + l15;
            attn[(((size_t)bb * S + i) * H + hh) * DH + d] = (ushort)f2bf(pacc[n][rg]);
        }
}

// ---------------------------------------------------------------------------
// launcher
// ---------------------------------------------------------------------------
extern "C" void kernel_launch(void* const* d_in, const int* in_sizes, int n_in,
                              void* d_out, int out_size, void* d_ws, size_t ws_size,
                              hipStream_t stream)
{
    (void)in_sizes; (void)n_in; (void)out_size; (void)ws_size;

    const float* x        = (const float*)d_in[0];
    const float* particles= (const float*)d_in[1];
    const float* wq       = (const float*)d_in[2];
    const float* wk       = (const float*)d_in[3];
    const float* wv       = (const float*)d_in[4];
    const float* dense_w  = (const float*)d_in[5];
    const float* dense_b  = (const float*)d_in[6];
    const float* c1k      = (const float*)d_in[7];
    const float* c1b      = (const float*)d_in[8];
    const float* c3k      = (const float*)d_in[9];
    const float* c3b      = (const float*)d_in[10];
    const float* c5k      = (const float*)d_in[11];
    const float* c5b      = (const float*)d_in[12];
    const float* mw1      = (const float*)d_in[13];
    const float* mb1      = (const float*)d_in[14];
    const float* mw2      = (const float*)d_in[15];
    const float* mb2      = (const float*)d_in[16];
    const float* mw3      = (const float*)d_in[17];
    const float* mb3      = (const float*)d_in[18];
    float* out = (float*)d_out;

    // workspace layout (ushort units unless noted), total ~120 MB
    ushort* xbf   = (ushort*)d_ws;                       //  8,388,608
    ushort* wt    = xbf   + (size_t)8388608;             //  1,048,576
    ushort* qb    = wt    + (size_t)1048576;             //  8,388,608
    ushort* kb    = qb    + (size_t)8388608;             //  8,388,608
    ushort* vbT   = kb    + (size_t)8388608;             //  8,388,608  [BH][DH][S]
    ushort* attnb = vbT   + (size_t)8388608;             //  8,388,608
    ushort* btf   = attnb + (size_t)8388608;             //    327,680  frag-linear
    ushort* vfrag = btf   + (size_t)327680;              //  8,388,608  frag-linear
    float*  mfrag = (float*)(vfrag + (size_t)8388608);   //  4,194,304 f32 frag-linear

    convert_x_kernel<<<dim3(4096), 256, 0, stream>>>(x, xbf);
    transpose_w_kernel<<<dim3(16, 16, 4), 256, 0, stream>>>(wq, wk, wv, dense_w, wt);
    build_toeplitz_frag_kernel<<<dim3(160), 256, 0, stream>>>(c1k, c3k, c5k, btf);
    pairwise_mlp_kernel<<<dim3(B * S), 256, 0, stream>>>(
        particles, mw1, mb1, mw2, mb2, mw3, mb3, c1b, c3b, c5b, mfrag);

    gemm_mfma_kernel<0><<<dim3(4, 128, 3), 256, 0, stream>>>(
        xbf, wt, qb, kb, vbT, nullptr, nullptr);
    vfrag_repack_kernel<<<dim3(4096), 256, 0, stream>>>(vbT, vfrag);

    fused_mfma_kernel<<<dim3(4, BH), 256, 0, stream>>>(
        qb, kb, vfrag, btf, mfrag, attnb);

    gemm_mfma_kernel<1><<<dim3(4, 128, 1), 256, 0, stream>>>(
        attnb, wt + (size_t)3 * DD * DD, nullptr, nullptr, nullptr, dense_b, out);
}